// Round 3
// baseline (290.309 us; speedup 1.0000x reference)
//
#include <hip/hip_runtime.h>
#include <math.h>

// Problem constants: y is (8, 3, 256, 512) fp32, lmbd is (1,3).
#define TVW 512      // row length
#define TVH 256      // H (for channel index)
#define TVC 3        // channels
#define WPB 2        // waves (= rows) per block; 3072 blocks -> 12 blk/CU, 24 waves/CU
#define BLOCK (WPB * 64)

// One wave per row; all 64 lanes redundantly run the same row's Condat state
// machine. v6 = v5 (counted inner loop, single ballot-break per element,
// scalar km/kp via ballot-selects) +
//  - manual unroll x4 of the extend loop: no yn/rn rotation moves, LDS
//    address arith amortized, xpp/rpp reads merge to ds_read2 issued a
//    block ahead
//  - yn carried across events: each handler reads the adjacent pair
//    x[k0n], x[k0n+1] (one ds_read2) issued BEFORE the flush stores, so
//    one overlapped wait per event instead of two dependent ones
//  - clean break when k0 walks past W-1 (removes garbage-driven spins)
// Output built in place in the LDS row; one coalesced float4 writeback.
__global__ __launch_bounds__(BLOCK)
void tv1d_condat_wave_kernel(const float* __restrict__ y,
                             const float* __restrict__ lmbd,
                             float* __restrict__ out,
                             int total_rows) {
    __shared__ __align__(16) float buf[WPB * TVW + 4];
    __shared__ float rtab[520];        // rtab[i] = 1/i (i>=1)
    const int tid  = threadIdx.x;
    const int wave = tid >> 6;
    const int lane = tid & 63;
    const int base_row = blockIdx.x * WPB;
    const int row = base_row + wave;

    // ---- stage WPB contiguous rows into LDS (coalesced float4) + recip table ----
    {
        float4* b4 = (float4*)buf;
        const float4* s4 = (const float4*)(y + (size_t)base_row * TVW);
        #pragma unroll
        for (int i = 0; i < (WPB * TVW / 4); i += BLOCK)
            b4[i + tid] = s4[i + tid];
    }
    for (int i = tid; i < 520; i += BLOCK)
        rtab[i] = 1.0f / (float)(i == 0 ? 1 : i);
    __syncthreads();

    if (row < total_rows) {
        const int c = (row / TVH) % TVC;
        float lam = log1pf(expf(lmbd[c]));   // softplus, once per row
        lam = __uint_as_float(__builtin_amdgcn_readfirstlane(__float_as_uint(lam)));
        const float nlam   = -lam;
        const float twolam = 2.0f * lam;
        float* x = buf + wave * TVW;         // in place; prefix [..k0) never re-read

        // Condat (2013) Algorithm 1 state. Inner loop always entered with k==k0.
        // k0/km/kp wave-uniform scalars (ballot-selected -> SGPR/SALU).
        int k0 = 0, km = 0, kp = 0;
        float vmin = x[0] - lam, vmax = x[0] + lam;
        float umin = lam, umax = nlam;
        float yn = x[1];                     // carried invariant: yn == x[k0+1]
        float umin_t, umax_t;

        for (int guard = 0; guard < 4096; ++guard) {
            const int trips = (TVW - 1) - k0;    // k0 <= W-1 always here
            float rn = 0.5f;                 // 1/den at den=2
            const float* xpp = x + (k0 + 2);
            const float* rpp = rtab + 3;
            const int kb = k0 + 1;           // element absorbed at trip t: kb + t

            int t = 0;

// absorb element kc = kb + t + J with value V, reciprocal R = 1/(den)
#define TVSTEP(J, V, R) \
            umin_t = umin + (V) - vmin; \
            umax_t = umax + (V) - vmax; \
            if (__ballot(fmaxf(-umin_t, umax_t) > lam)) goto midjump; \
            { const int kc = kb + t + (J); \
              km = __ballot(umin_t >= lam)  ? kc : km;   /* s_cselect */ \
              kp = __ballot(umax_t <= nlam) ? kc : kp; \
              const float umin_n = fminf(umin_t, lam); \
              const float umax_n = fmaxf(umax_t, nlam); \
              vmin = fmaf(umin_t - umin_n, (R), vmin);   /* == fma(max(umin_t-lam,0),rn,vmin) */ \
              vmax = fmaf(umax_t - umax_n, (R), vmax);   /* == fma(min(umax_t+lam,0),rn,vmax) */ \
              umin = umin_n; umax = umax_n; }

            // ---- unrolled x4 extend loop ----
            for (; t < trips - 3; t += 4) {
                const float a0 = xpp[t+0], a1 = xpp[t+1], a2 = xpp[t+2], a3 = xpp[t+3];
                const float r0 = rpp[t+0], r1 = rpp[t+1], r2 = rpp[t+2], r3 = rpp[t+3];
                TVSTEP(0, yn, rn)
                TVSTEP(1, a0, r0)
                TVSTEP(2, a1, r1)
                TVSTEP(3, a2, r2)
                yn = a3; rn = r3;
            }
            // ---- remainder (<= 3) ----
            for (; t < trips; ++t) {
                const float a0 = xpp[t];
                const float r0 = rpp[t];
                TVSTEP(0, yn, rn)
                yn = a0; rn = r0;
            }
#undef TVSTEP

            // ---- boundary: k == W-1, den = trips+1 ----
            if (__ballot(umin < 0.0f)) {         // flush [k0..km] at vmin; keep kp,vmax
                const int k0n = km + 1;
                const int pe = km < TVW - 1 ? km : TVW - 1;
                float nv = 0.0f, nyn = 0.0f;
                if (k0n < TVW) { nv = x[k0n]; nyn = x[k0n + 1]; }  // reads before stores
                for (int p = k0 + lane; p <= pe; p += 64) x[p] = vmin;
                if (k0n >= TVW) break;           // whole row written
                k0 = k0n; km = k0n;
                vmin = nv;
                yn = nyn;
                umax = vmin + lam - vmax;
                umin = lam;
            } else if (__ballot(umax > 0.0f)) {  // flush [k0..kp] at vmax; keep km,vmin
                const int k0n = kp + 1;
                const int pe = kp < TVW - 1 ? kp : TVW - 1;
                float nv = 0.0f, nyn = 0.0f;
                if (k0n < TVW) { nv = x[k0n]; nyn = x[k0n + 1]; }
                for (int p = k0 + lane; p <= pe; p += 64) x[p] = vmax;
                if (k0n >= TVW) break;
                k0 = k0n; kp = k0n;
                vmax = nv;
                yn = nyn;
                umin = vmax + nlam - vmin;
                umax = nlam;
            } else {                             // terminate: flush tail at mean value
                const float v = vmin + umin * rtab[trips + 1];
                for (int p = k0 + lane; p < TVW; p += 64) x[p] = v;
                break;
            }
            continue;

midjump:    // jump detected while absorbing; state is pre-absorb (matches v5)
            if (__ballot(umin_t < nlam)) {       // negative jump: flush [k0..km] at vmin
                const int k0n = km + 1;          // km <= W-2 here
                const float nv  = x[k0n];        // adjacent pair -> ds_read2,
                const float nyn = x[k0n + 1];    // issued before the flush stores
                for (int p = k0 + lane; p <= km; p += 64) x[p] = vmin;
                k0 = k0n; km = kp = k0n;
                vmin = nv;
                vmax = nv + twolam;
                yn = nyn;                        // pad-safe (k0n+1 <= W)
            } else {                             // positive jump: flush [k0..kp] at vmax
                const int k0n = kp + 1;          // kp <= W-2 here
                const float nv  = x[k0n];
                const float nyn = x[k0n + 1];
                for (int p = k0 + lane; p <= kp; p += 64) x[p] = vmax;
                k0 = k0n; km = kp = k0n;
                vmax = nv;
                vmin = nv - twolam;
                yn = nyn;
            }
            umin = lam; umax = nlam;
        }
    }
    __syncthreads();

    // ---- coalesced float4 writeback LDS -> out ----
    {
        float4* b4 = (float4*)buf;
        float4* d4 = (float4*)(out + (size_t)base_row * TVW);
        #pragma unroll
        for (int i = 0; i < (WPB * TVW / 4); i += BLOCK)
            d4[i + tid] = b4[i + tid];
    }
}

extern "C" void kernel_launch(void* const* d_in, const int* in_sizes, int n_in,
                              void* d_out, int out_size, void* d_ws, size_t ws_size,
                              hipStream_t stream) {
    const float* y    = (const float*)d_in[0];
    const float* lmbd = (const float*)d_in[1];
    float* out = (float*)d_out;

    const int total_rows = in_sizes[0] / TVW;              // 6144
    const int grid = (total_rows + WPB - 1) / WPB;         // 3072 blocks
    tv1d_condat_wave_kernel<<<grid, BLOCK, 0, stream>>>(y, lmbd, out, total_rows);
}

// Round 4
// 276.022 us; speedup vs baseline: 1.0518x; 1.0518x over previous
//
#include <hip/hip_runtime.h>
#include <math.h>

// Problem constants: y is (8, 3, 256, 512) fp32, lmbd is (1,3).
#define TVW 512      // row length
#define TVH 256      // H (for channel index)
#define TVC 3        // channels
#define WPB 2        // waves (= rows) per block; 3072 blocks -> 12 blk/CU, 24 waves/CU
#define BLOCK (WPB * 64)

// One wave per row. v7 = round-2 structure (counted inner loop, one ballot
// break per element -- benched 229 us dispatch) + HALF-WAVE WALK FUSION:
// Condat's min-walk and max-walk are exact sign mirrors. With U=-umax,
// V=-vmax and a negated LDS copy of the row, the max-walk is the SAME
// instruction sequence as the min-walk. Lanes 0-31 run (umin,vmin) on x,
// lanes 32-63 run (U,V) on xneg -> every VALU op serves both walks:
//   u_t = u + yn - v        : umin_t  and  -umax_t
//   u_t <  -lam (one v_cmp) : ballot lo = neg-jump, hi = pos-jump
//   u_t >=  lam (one v_cmp) : ballot lo -> km,      hi -> kp
//   u_n = min(u_t,lam); v += (u_t-u_n)*rn : both clamps
//   u  <  0    (boundary)   : lo = umin<0, hi = umax>0
// Negation is IEEE-exact, so the lo half is bitwise-identical to round 2
// and all branch decisions unchanged. xneg is never flushed (flushed
// positions are never re-read), so it stays valid as a read source.
// Output built in place in the x row; one coalesced float4 writeback.
__global__ __launch_bounds__(BLOCK)
void tv1d_condat_wave_kernel(const float* __restrict__ y,
                             const float* __restrict__ lmbd,
                             float* __restrict__ out,
                             int total_rows) {
    __shared__ __align__(16) float buf [WPB * TVW + 4];   // primary rows (output)
    __shared__ __align__(16) float bneg[WPB * TVW + 4];   // negated copy (read-only)
    __shared__ float rtab[520];        // rtab[i] = 1/i (i>=1)
    const int tid  = threadIdx.x;
    const int wave = tid >> 6;
    const int lane = tid & 63;
    const bool hi  = lane >= 32;
    const int base_row = blockIdx.x * WPB;
    const int row = base_row + wave;

    // ---- stage rows + negated copy into LDS (coalesced float4) + recip table ----
    {
        float4* b4 = (float4*)buf;
        float4* n4 = (float4*)bneg;
        const float4* s4 = (const float4*)(y + (size_t)base_row * TVW);
        #pragma unroll
        for (int i = 0; i < (WPB * TVW / 4); i += BLOCK) {
            const float4 v = s4[i + tid];
            b4[i + tid] = v;
            n4[i + tid] = make_float4(-v.x, -v.y, -v.z, -v.w);
        }
    }
    for (int i = tid; i < 520; i += BLOCK)
        rtab[i] = 1.0f / (float)(i == 0 ? 1 : i);
    if (tid < 4) {                       // init pads (never used in decisions)
        buf [WPB * TVW + tid] = 0.0f;
        bneg[WPB * TVW + tid] = 0.0f;
    }
    __syncthreads();

    if (row < total_rows) {
        const int c = (row / TVH) % TVC;
        float lam = log1pf(expf(lmbd[c]));   // softplus, once per row
        lam = __uint_as_float(__builtin_amdgcn_readfirstlane(__float_as_uint(lam)));
        const float nlam   = -lam;
        const float twolam = 2.0f * lam;
        float* x = buf + wave * TVW;         // output row; prefix [..k0) never re-read
        const float* xs = hi ? (bneg + wave * TVW) : (buf + wave * TVW); // signed source
        const float cneg = hi ? twolam : 0.0f;  // v' = ownload - cneg after neg jump
        const float cpos = hi ? 0.0f : twolam;  // v' = ownload - cpos after pos jump

        // Packed walk state: lo lanes hold (umin,vmin); hi lanes hold (-umax,-vmax).
        // k0/km/kp wave-uniform scalars (ballot-half selected -> SGPR/SALU).
        int k0 = 0, km = 0, kp = 0;
        float v = xs[0] - lam;               // lo: y0-lam ; hi: -(y0+lam)
        float u = lam;                       // lo: lam    ; hi: -(-lam) = lam
        float yn = xs[1];                    // invariant: yn == xs[k0+1]

        for (int guard = 0; guard < 4096; ++guard) {
            const int trips = (TVW - 1) - k0;    // k0 <= W-1 always here
            float rn = 0.5f;                 // 1/den at den=2
            const float* xpp = xs + (k0 + 2);
            const float* rpp = rtab + 3;
            const int kb = k0 + 1;           // element absorbed at trip t: kb + t

            unsigned long long jb = 0;
            int t = 0;
            for (; t < trips; ++t) {
                const float yn2 = xpp[t];    // xs[k0+2+t], pad-safe
                const float rn2 = rpp[t];    // rtab[3+t] = 1/(t+3)
                const float u_t = u + yn - v;
                jb = __ballot(u_t < nlam);   // lo: umin_t<-lam, hi: umax_t>lam
                if (jb) break;
                const unsigned long long cb = __ballot(u_t >= lam); // lo: km, hi: kp
                const int kc = kb + t;
                km = (unsigned)(cb)       ? kc : km;   // s_cselect
                kp = (unsigned)(cb >> 32) ? kc : kp;
                const float u_n = fminf(u_t, lam);
                v = fmaf(u_t - u_n, rn, v);  // both clamp corrections
                u = u_n;
                yn = yn2; rn = rn2;
            }

            if (t < trips) {
                // ---- mid-row jump; jb lo bits = negative (priority), hi = positive ----
                if ((unsigned)jb) {          // negative jump: flush [k0..km] at vmin
                    const int k0n = km + 1;  // km <= W-2 here
                    const float fv  = __shfl(v, 0);        // vmin (broadcast lane 0)
                    const float nvl = xs[k0n];             // adjacent pair -> ds_read2,
                    const float ynn = xs[k0n + 1];         // issued before the stores
                    for (int p = k0 + lane; p <= km; p += 64) x[p] = fv;
                    k0 = k0n; km = kp = k0n;
                    v = nvl - cneg;          // lo: nv ; hi: -nv-2lam == -(nv+2lam)
                    yn = ynn;
                } else {                     // positive jump: flush [k0..kp] at vmax
                    const int k0n = kp + 1;  // kp <= W-2 here
                    const float fv  = -__shfl(v, 32);      // vmax = -V(lane 32)
                    const float nvl = xs[k0n];
                    const float ynn = xs[k0n + 1];
                    for (int p = k0 + lane; p <= kp; p += 64) x[p] = fv;
                    k0 = k0n; km = kp = k0n;
                    v = nvl - cpos;          // lo: nv-2lam ; hi: -nv
                    yn = ynn;
                }
                u = lam;                     // lo: lam ; hi: -(-lam)
            } else {
                // ---- boundary: k == W-1, den = trips+1 ----
                const unsigned long long bb = __ballot(u < 0.0f); // lo: umin<0, hi: umax>0
                if ((unsigned)bb) {          // flush [k0..km] at vmin; keep vmax/kp
                    const int k0n = km + 1;
                    const float fv = __shfl(v, 0);
                    float nvl = 0.0f, ynn = 0.0f;
                    if (k0n < TVW) { nvl = xs[k0n]; ynn = xs[k0n + 1]; }
                    const int pe = km < TVW - 1 ? km : TVW - 1;
                    for (int p = k0 + lane; p <= pe; p += 64) x[p] = fv;
                    if (k0n >= TVW) break;   // whole row written
                    // lo: u'=lam, v'=nv ; hi: U'=(-nv-lam)-V_old, V'=V_old
                    const float tt = nvl - lam;      // hi: -nv-lam (exact -(nv+lam))
                    u = hi ? (tt - v) : lam;
                    v = hi ? v : nvl;
                    yn = ynn;
                    k0 = k0n; km = k0n;
                } else if ((unsigned)(bb >> 32)) {   // flush [k0..kp] at vmax; keep vmin/km
                    const int k0n = kp + 1;
                    const float fv = -__shfl(v, 32);
                    float nvl = 0.0f, ynn = 0.0f;
                    if (k0n < TVW) { nvl = xs[k0n]; ynn = xs[k0n + 1]; }
                    const int pe = kp < TVW - 1 ? kp : TVW - 1;
                    for (int p = k0 + lane; p <= pe; p += 64) x[p] = fv;
                    if (k0n >= TVW) break;
                    // lo: u'=(nv-lam)-vmin, v'=vmin ; hi: U'=lam, V'=-nv=ownload
                    const float tt = nvl - lam;      // lo: nv-lam (== vmax'+nlam)
                    u = hi ? lam : (tt - v);
                    v = hi ? nvl : v;
                    yn = ynn;
                    k0 = k0n; kp = k0n;
                } else {                     // terminate: flush tail at mean value
                    const float vt = fmaf(u, rtab[trips + 1], v); // lo: vmin+umin*r
                    const float fv = __shfl(vt, 0);
                    for (int p = k0 + lane; p < TVW; p += 64) x[p] = fv;
                    break;
                }
            }
        }
    }
    __syncthreads();

    // ---- coalesced float4 writeback LDS -> out ----
    {
        float4* b4 = (float4*)buf;
        float4* d4 = (float4*)(out + (size_t)base_row * TVW);
        #pragma unroll
        for (int i = 0; i < (WPB * TVW / 4); i += BLOCK)
            d4[i + tid] = b4[i + tid];
    }
}

extern "C" void kernel_launch(void* const* d_in, const int* in_sizes, int n_in,
                              void* d_out, int out_size, void* d_ws, size_t ws_size,
                              hipStream_t stream) {
    const float* y    = (const float*)d_in[0];
    const float* lmbd = (const float*)d_in[1];
    float* out = (float*)d_out;

    const int total_rows = in_sizes[0] / TVW;              // 6144
    const int grid = (total_rows + WPB - 1) / WPB;         // 3072 blocks
    tv1d_condat_wave_kernel<<<grid, BLOCK, 0, stream>>>(y, lmbd, out, total_rows);
}

// Round 5
// 245.096 us; speedup vs baseline: 1.1845x; 1.1262x over previous
//
#include <hip/hip_runtime.h>
#include <math.h>

// Problem constants: y is (8, 3, 256, 512) fp32, lmbd is (1,3).
#define TVW 512      // row length
#define TVH 256      // H (for channel index)
#define TVC 3        // channels
#define WPB 2        // waves (= rows) per block; 3072 blocks -> 12 blk/CU, 24 waves/CU
#define BLOCK (WPB * 64)
#define PAD 12       // ahead-load overrun room (max idx k0+t+16 <= 523 = TVW+11)

// One wave per row. v8 = v7 (half-wave walk fusion: lanes 0-31 run the
// min-walk on x, lanes 32-63 run the sign-mirrored max-walk on -x, so every
// VALU op serves both walks; ballot lo/hi halves give both decisions) +
// LATENCY FIX. v7 counters showed VALUBusy 48% with stalls growing as issue
// shrank: each iteration exposed ~90cy of ds_read latency (loads issued one
// ~28cy iteration ahead of use). Changes:
//  - rn stream removed: den<=9 uses exact literal reciprocals (bitwise =
//    old rtab), den>=10 uses v_rcp (<=1ulp, tolerance-safe, same value in
//    both halves so the sign-mirror stays exact)
//  - yn stream 12-deep: 3 banks x 4 regs, each bank reloaded 12 ahead right
//    after consumption -> ~8 steps (~150cy) of slack >= 120cy LDS latency
//  - event handlers issue the full 13-reg refill (nv + P/Q/R) at entry,
//    before the flush stores: one pipelined latency per event
// Output built in place in the x row; one coalesced float4 writeback.
__global__ __launch_bounds__(BLOCK)
void tv1d_condat_wave_kernel(const float* __restrict__ y,
                             const float* __restrict__ lmbd,
                             float* __restrict__ out,
                             int total_rows) {
    __shared__ __align__(16) float buf [WPB * TVW + PAD];   // primary rows (output)
    __shared__ __align__(16) float bneg[WPB * TVW + PAD];   // negated copy (read-only)
    const int tid  = threadIdx.x;
    const int wave = tid >> 6;
    const int lane = tid & 63;
    const bool hi  = lane >= 32;
    const int base_row = blockIdx.x * WPB;
    const int row = base_row + wave;

    // ---- stage rows + negated copy into LDS (coalesced float4) ----
    {
        float4* b4 = (float4*)buf;
        float4* n4 = (float4*)bneg;
        const float4* s4 = (const float4*)(y + (size_t)base_row * TVW);
        #pragma unroll
        for (int i = 0; i < (WPB * TVW / 4); i += BLOCK) {
            const float4 v = s4[i + tid];
            b4[i + tid] = v;
            n4[i + tid] = make_float4(-v.x, -v.y, -v.z, -v.w);
        }
    }
    if (tid < PAD) {                     // pads: loaded into regs but never consumed
        buf [WPB * TVW + tid] = 0.0f;
        bneg[WPB * TVW + tid] = 0.0f;
    }
    __syncthreads();

    if (row < total_rows) {
        const int c = (row / TVH) % TVC;
        float lam = log1pf(expf(lmbd[c]));   // softplus, once per row
        lam = __uint_as_float(__builtin_amdgcn_readfirstlane(__float_as_uint(lam)));
        const float nlam   = -lam;
        const float twolam = 2.0f * lam;
        float* x = buf + wave * TVW;         // output row; prefix [..k0) never re-read
        const float* xs = hi ? (bneg + wave * TVW) : (buf + wave * TVW); // signed source
        const float cneg = hi ? twolam : 0.0f;  // v' = ownload - cneg after neg jump
        const float cpos = hi ? 0.0f : twolam;  // v' = ownload - cpos after pos jump

        // All cross-label state declared up-front (goto-safe).
        int k0, km, kp, t, trips, rem, seg_guard;
        unsigned long long jb;
        float u, v, nv, fv, tt, den_f;
        float P0, P1, P2, P3, Q0, Q1, Q2, Q3, R0, R1, R2, R3, e0, e1, e2;
        bool negj;

        // Packed walk state: lo lanes hold (umin,vmin); hi lanes hold (-umax,-vmax).
        k0 = 0; km = 0; kp = 0; seg_guard = 2048; jb = 0;
        v = xs[0] - lam;                 // lo: y0-lam ; hi: -(y0+lam)
        u = lam;
        P0 = xs[1];  P1 = xs[2];  P2 = xs[3];  P3 = xs[4];
        Q0 = xs[5];  Q1 = xs[6];  Q2 = xs[7];  Q3 = xs[8];
        R0 = xs[9];  R1 = xs[10]; R2 = xs[11]; R3 = xs[12];

// absorb one element: EV = xs[KC], RN = 1/den for this step
#define TVSTEP(EV, RN, KC) { \
            const float u_t = u + (EV) - v; \
            jb = __ballot(u_t < nlam);   /* lo: umin_t<-lam, hi: umax_t>lam */ \
            if (jb) goto midjump; \
            const unsigned long long cb = __ballot(u_t >= lam); /* lo->km, hi->kp */ \
            const int kc_ = (KC); \
            km = (unsigned)(cb)       ? kc_ : km;   /* s_cselect */ \
            kp = (unsigned)(cb >> 32) ? kc_ : kp; \
            const float u_n = fminf(u_t, lam); \
            v = fmaf(u_t - u_n, (RN), v);  /* both clamp corrections */ \
            u = u_n; }

// one steady-state phase: 4 steps off bank B, then reload B 12 ahead
#define TVPHASE(B0_, B1_, B2_, B3_) { \
            den_f = (float)(t + 2); \
            TVSTEP(B0_, __builtin_amdgcn_rcpf(den_f),        k0 + t + 1) \
            TVSTEP(B1_, __builtin_amdgcn_rcpf(den_f + 1.0f), k0 + t + 2) \
            TVSTEP(B2_, __builtin_amdgcn_rcpf(den_f + 2.0f), k0 + t + 3) \
            TVSTEP(B3_, __builtin_amdgcn_rcpf(den_f + 3.0f), k0 + t + 4) \
            B0_ = xs[k0 + t + 13]; B1_ = xs[k0 + t + 14]; \
            B2_ = xs[k0 + t + 15]; B3_ = xs[k0 + t + 16]; \
            t += 4; }

seg_start:
        if (--seg_guard < 0) goto done;      // safety; k0 strictly increases
        trips = (TVW - 1) - k0;
        if (trips < 4) { t = 0; e0 = P0; e1 = P1; e2 = P2; goto rem_steps; }
        // ---- peel block 0 (t=0..3), exact literal reciprocals ----
        TVSTEP(P0, 0.5f,           k0 + 1)
        TVSTEP(P1, (1.0f / 3.0f),  k0 + 2)
        TVSTEP(P2, 0.25f,          k0 + 3)
        TVSTEP(P3, 0.2f,           k0 + 4)
        P0 = xs[k0 + 13]; P1 = xs[k0 + 14]; P2 = xs[k0 + 15]; P3 = xs[k0 + 16];
        if (trips < 8) { t = 4; e0 = Q0; e1 = Q1; e2 = Q2; goto rem_steps; }
        // ---- peel block 1 (t=4..7) ----
        TVSTEP(Q0, (1.0f / 6.0f),  k0 + 5)
        TVSTEP(Q1, (1.0f / 7.0f),  k0 + 6)
        TVSTEP(Q2, 0.125f,         k0 + 7)
        TVSTEP(Q3, (1.0f / 9.0f),  k0 + 8)
        Q0 = xs[k0 + 17]; Q1 = xs[k0 + 18]; Q2 = xs[k0 + 19]; Q3 = xs[k0 + 20];
        t = 8;
        // ---- steady three-phase loop (bank order R, P, Q) ----
        for (;;) {
            if (t + 4 > trips) { e0 = R0; e1 = R1; e2 = R2; break; }
            TVPHASE(R0, R1, R2, R3)
            if (t + 4 > trips) { e0 = P0; e1 = P1; e2 = P2; break; }
            TVPHASE(P0, P1, P2, P3)
            if (t + 4 > trips) { e0 = Q0; e1 = Q1; e2 = Q2; break; }
            TVPHASE(Q0, Q1, Q2, Q3)
        }
rem_steps:
        rem = trips - t;                     // 0..3
        if (rem > 0) {
            den_f = (float)(t + 2);
            TVSTEP(e0, __builtin_amdgcn_rcpf(den_f), k0 + t + 1)
            if (rem > 1) {
                TVSTEP(e1, __builtin_amdgcn_rcpf(den_f + 1.0f), k0 + t + 2)
                if (rem > 2) {
                    TVSTEP(e2, __builtin_amdgcn_rcpf(den_f + 2.0f), k0 + t + 3)
                }
            }
        }

        // ---- boundary: k == W-1, den = trips+1 ----
        {
            const unsigned long long bb = __ballot(u < 0.0f); // lo: umin<0, hi: umax>0
            if ((unsigned)bb) {              // flush [k0..km] at vmin; keep vmax/kp
                const int k0n = km + 1;
                fv = __shfl(v, 0);
                if (k0n < TVW) {             // refill issued before the stores
                    nv = xs[k0n];
                    P0 = xs[k0n + 1];  P1 = xs[k0n + 2];  P2 = xs[k0n + 3];  P3 = xs[k0n + 4];
                    Q0 = xs[k0n + 5];  Q1 = xs[k0n + 6];  Q2 = xs[k0n + 7];  Q3 = xs[k0n + 8];
                    R0 = xs[k0n + 9];  R1 = xs[k0n + 10]; R2 = xs[k0n + 11]; R3 = xs[k0n + 12];
                }
                { const int pe = km < TVW - 1 ? km : TVW - 1;
                  for (int p = k0 + lane; p <= pe; p += 64) x[p] = fv; }
                if (k0n >= TVW) goto done;
                // lo: u'=lam, v'=nv ; hi: U'=(-nv-lam)-V_old, V'=V_old
                tt = nv - lam;
                u = hi ? (tt - v) : lam;
                v = hi ? v : nv;
                k0 = k0n; km = k0n;
                goto seg_start;
            } else if ((unsigned)(bb >> 32)) { // flush [k0..kp] at vmax; keep vmin/km
                const int k0n = kp + 1;
                fv = -__shfl(v, 32);
                if (k0n < TVW) {
                    nv = xs[k0n];
                    P0 = xs[k0n + 1];  P1 = xs[k0n + 2];  P2 = xs[k0n + 3];  P3 = xs[k0n + 4];
                    Q0 = xs[k0n + 5];  Q1 = xs[k0n + 6];  Q2 = xs[k0n + 7];  Q3 = xs[k0n + 8];
                    R0 = xs[k0n + 9];  R1 = xs[k0n + 10]; R2 = xs[k0n + 11]; R3 = xs[k0n + 12];
                }
                { const int pe = kp < TVW - 1 ? kp : TVW - 1;
                  for (int p = k0 + lane; p <= pe; p += 64) x[p] = fv; }
                if (k0n >= TVW) goto done;
                // lo: u'=(nv-lam)-vmin, v'=vmin ; hi: U'=lam, V'=-nv
                tt = nv - lam;
                u = hi ? lam : (tt - v);
                v = hi ? nv : v;
                k0 = k0n; kp = k0n;
                goto seg_start;
            } else {                         // terminate: flush tail at mean value
                const float vt = fmaf(u, __builtin_amdgcn_rcpf((float)(trips + 1)), v);
                fv = __shfl(vt, 0);
                for (int p = k0 + lane; p < TVW; p += 64) x[p] = fv;
                goto done;
            }
        }

midjump: // jump while absorbing; jb lo bits = negative (priority), hi = positive
        {
            negj = (unsigned)jb != 0;
            const int fe = negj ? km : kp;   // flush end (scalar); fe <= W-2 here
            const int k0n = fe + 1;
            const float b0  = __shfl(v, 0);          // vmin
            const float b32 = __shfl(v, 32);         // -vmax
            fv = negj ? b0 : -b32;
            nv = xs[k0n];                    // refill issued before the stores
            P0 = xs[k0n + 1];  P1 = xs[k0n + 2];  P2 = xs[k0n + 3];  P3 = xs[k0n + 4];
            Q0 = xs[k0n + 5];  Q1 = xs[k0n + 6];  Q2 = xs[k0n + 7];  Q3 = xs[k0n + 8];
            R0 = xs[k0n + 9];  R1 = xs[k0n + 10]; R2 = xs[k0n + 11]; R3 = xs[k0n + 12];
            for (int p = k0 + lane; p <= fe; p += 64) x[p] = fv;
            k0 = k0n; km = k0n; kp = k0n;
            v = nv - (negj ? cneg : cpos);   // lo/hi restart values (v7 algebra)
            u = lam;
            goto seg_start;
        }
#undef TVPHASE
#undef TVSTEP
done:   ;
    }
    __syncthreads();

    // ---- coalesced float4 writeback LDS -> out ----
    {
        float4* b4 = (float4*)buf;
        float4* d4 = (float4*)(out + (size_t)base_row * TVW);
        #pragma unroll
        for (int i = 0; i < (WPB * TVW / 4); i += BLOCK)
            d4[i + tid] = b4[i + tid];
    }
}

extern "C" void kernel_launch(void* const* d_in, const int* in_sizes, int n_in,
                              void* d_out, int out_size, void* d_ws, size_t ws_size,
                              hipStream_t stream) {
    const float* y    = (const float*)d_in[0];
    const float* lmbd = (const float*)d_in[1];
    float* out = (float*)d_out;

    const int total_rows = in_sizes[0] / TVW;              // 6144
    const int grid = (total_rows + WPB - 1) / WPB;         // 3072 blocks
    tv1d_condat_wave_kernel<<<grid, BLOCK, 0, stream>>>(y, lmbd, out, total_rows);
}

// Round 6
// 237.048 us; speedup vs baseline: 1.2247x; 1.0340x over previous
//
#include <hip/hip_runtime.h>
#include <math.h>

// Problem constants: y is (8, 3, 256, 512) fp32, lmbd is (1,3).
#define TVW 512      // row length
#define TVH 256      // H (for channel index)
#define TVC 3        // channels
#define WPB 2        // waves (= rows) per block; 3072 blocks -> 12 blk/CU, 24 waves/CU
#define BLOCK (WPB * 64)
#define PAD 12       // ahead-load overrun room (max idx k0+t+16 <= 523 = TVW+11)

// One wave per row. v9 = v8 (half-wave walk fusion + 12-deep 3-bank prefetch
// + literal/rcp reciprocals; benched 198us dispatch, VALUBusy 57%) minus all
// cross-lane traffic:
//  - __shfl broadcasts removed: lo lanes all hold vmin, hi lanes all hold
//    -vmax, so the flush value is always natively present in the half that
//    writes it. Neg-jump flush: lo half stores v (stride 32). Pos-jump
//    flush: hi half stores -v. Terminate: lo half stores fma(u,rcp,v).
//    This deletes ~30-40cy of ds_bpermute+wait from every event's critical
//    path (~250 events/row).
//  - per-wave staging/writeback (2 float4/lane): both __syncthreads gone,
//    waves fully decoupled -- fast wave frees its SIMD slots immediately.
//    Ahead-reads bleeding into the neighbor row / pad are benign (never
//    consumed; LDS allocation covers them).
// Output built in place in the x row; coalesced float4 writeback per wave.
__global__ __launch_bounds__(BLOCK)
void tv1d_condat_wave_kernel(const float* __restrict__ y,
                             const float* __restrict__ lmbd,
                             float* __restrict__ out,
                             int total_rows) {
    __shared__ __align__(16) float buf [WPB * TVW + PAD];   // primary rows (output)
    __shared__ __align__(16) float bneg[WPB * TVW + PAD];   // negated copy (read-only)
    const int tid  = threadIdx.x;
    const int wave = tid >> 6;
    const int lane = tid & 63;
    const int l32  = lane & 31;
    const bool hi  = lane >= 32;
    const int row  = blockIdx.x * WPB + wave;

    if (row < total_rows) {
        // ---- per-wave staging: own row + negated copy (coalesced float4) ----
        {
            const float4* s4 = (const float4*)(y + (size_t)row * TVW);
            float4* b4 = (float4*)(buf  + wave * TVW);
            float4* n4 = (float4*)(bneg + wave * TVW);
            #pragma unroll
            for (int i = 0; i < TVW / 4; i += 64) {
                const float4 vv = s4[i + lane];
                b4[i + lane] = vv;
                n4[i + lane] = make_float4(-vv.x, -vv.y, -vv.z, -vv.w);
            }
        }

        const int c = (row / TVH) % TVC;
        float lam = log1pf(expf(lmbd[c]));   // softplus, once per row
        lam = __uint_as_float(__builtin_amdgcn_readfirstlane(__float_as_uint(lam)));
        const float nlam   = -lam;
        const float twolam = 2.0f * lam;
        float* x = buf + wave * TVW;         // output row; prefix [..k0) never re-read
        const float* xs = hi ? (bneg + wave * TVW) : (buf + wave * TVW); // signed source
        const float cneg = hi ? twolam : 0.0f;  // v' = ownload - cneg after neg jump
        const float cpos = hi ? 0.0f : twolam;  // v' = ownload - cpos after pos jump

        // All cross-label state declared up-front (goto-safe).
        int k0, km, kp, t, trips, rem, seg_guard;
        unsigned long long jb;
        float u, v, nv, tt, wv, den_f;
        float P0, P1, P2, P3, Q0, Q1, Q2, Q3, R0, R1, R2, R3, e0, e1, e2;
        bool negj;

        // Packed walk state: lo lanes hold (umin,vmin); hi lanes hold (-umax,-vmax).
        k0 = 0; km = 0; kp = 0; seg_guard = 2048; jb = 0;
        v = xs[0] - lam;                 // lo: y0-lam ; hi: -(y0+lam)
        u = lam;
        P0 = xs[1];  P1 = xs[2];  P2 = xs[3];  P3 = xs[4];
        Q0 = xs[5];  Q1 = xs[6];  Q2 = xs[7];  Q3 = xs[8];
        R0 = xs[9];  R1 = xs[10]; R2 = xs[11]; R3 = xs[12];

// absorb one element: EV = xs[KC], RN = 1/den for this step
#define TVSTEP(EV, RN, KC) { \
            const float u_t = u + (EV) - v; \
            jb = __ballot(u_t < nlam);   /* lo: umin_t<-lam, hi: umax_t>lam */ \
            if (jb) goto midjump; \
            const unsigned long long cb = __ballot(u_t >= lam); /* lo->km, hi->kp */ \
            const int kc_ = (KC); \
            km = (unsigned)(cb)       ? kc_ : km;   /* s_cselect */ \
            kp = (unsigned)(cb >> 32) ? kc_ : kp; \
            const float u_n = fminf(u_t, lam); \
            v = fmaf(u_t - u_n, (RN), v);  /* both clamp corrections */ \
            u = u_n; }

// one steady-state phase: 4 steps off bank B, then reload B 12 ahead
#define TVPHASE(B0_, B1_, B2_, B3_) { \
            den_f = (float)(t + 2); \
            TVSTEP(B0_, __builtin_amdgcn_rcpf(den_f),        k0 + t + 1) \
            TVSTEP(B1_, __builtin_amdgcn_rcpf(den_f + 1.0f), k0 + t + 2) \
            TVSTEP(B2_, __builtin_amdgcn_rcpf(den_f + 2.0f), k0 + t + 3) \
            TVSTEP(B3_, __builtin_amdgcn_rcpf(den_f + 3.0f), k0 + t + 4) \
            B0_ = xs[k0 + t + 13]; B1_ = xs[k0 + t + 14]; \
            B2_ = xs[k0 + t + 15]; B3_ = xs[k0 + t + 16]; \
            t += 4; }

seg_start:
        if (--seg_guard < 0) goto done;      // safety; k0 strictly increases
        trips = (TVW - 1) - k0;
        if (trips < 4) { t = 0; e0 = P0; e1 = P1; e2 = P2; goto rem_steps; }
        // ---- peel block 0 (t=0..3), exact literal reciprocals ----
        TVSTEP(P0, 0.5f,           k0 + 1)
        TVSTEP(P1, (1.0f / 3.0f),  k0 + 2)
        TVSTEP(P2, 0.25f,          k0 + 3)
        TVSTEP(P3, 0.2f,           k0 + 4)
        P0 = xs[k0 + 13]; P1 = xs[k0 + 14]; P2 = xs[k0 + 15]; P3 = xs[k0 + 16];
        if (trips < 8) { t = 4; e0 = Q0; e1 = Q1; e2 = Q2; goto rem_steps; }
        // ---- peel block 1 (t=4..7) ----
        TVSTEP(Q0, (1.0f / 6.0f),  k0 + 5)
        TVSTEP(Q1, (1.0f / 7.0f),  k0 + 6)
        TVSTEP(Q2, 0.125f,         k0 + 7)
        TVSTEP(Q3, (1.0f / 9.0f),  k0 + 8)
        Q0 = xs[k0 + 17]; Q1 = xs[k0 + 18]; Q2 = xs[k0 + 19]; Q3 = xs[k0 + 20];
        t = 8;
        // ---- steady three-phase loop (bank order R, P, Q) ----
        for (;;) {
            if (t + 4 > trips) { e0 = R0; e1 = R1; e2 = R2; break; }
            TVPHASE(R0, R1, R2, R3)
            if (t + 4 > trips) { e0 = P0; e1 = P1; e2 = P2; break; }
            TVPHASE(P0, P1, P2, P3)
            if (t + 4 > trips) { e0 = Q0; e1 = Q1; e2 = Q2; break; }
            TVPHASE(Q0, Q1, Q2, Q3)
        }
rem_steps:
        rem = trips - t;                     // 0..3
        if (rem > 0) {
            den_f = (float)(t + 2);
            TVSTEP(e0, __builtin_amdgcn_rcpf(den_f), k0 + t + 1)
            if (rem > 1) {
                TVSTEP(e1, __builtin_amdgcn_rcpf(den_f + 1.0f), k0 + t + 2)
                if (rem > 2) {
                    TVSTEP(e2, __builtin_amdgcn_rcpf(den_f + 2.0f), k0 + t + 3)
                }
            }
        }

        // ---- boundary: k == W-1, den = trips+1 ----
        {
            const unsigned long long bb = __ballot(u < 0.0f); // lo: umin<0, hi: umax>0
            if ((unsigned)bb) {              // flush [k0..km] at vmin; keep vmax/kp
                const int k0n = km + 1;
                wv = v;                      // lo lanes hold vmin natively
                if (k0n < TVW) {             // refill issued before the stores
                    nv = xs[k0n];
                    P0 = xs[k0n + 1];  P1 = xs[k0n + 2];  P2 = xs[k0n + 3];  P3 = xs[k0n + 4];
                    Q0 = xs[k0n + 5];  Q1 = xs[k0n + 6];  Q2 = xs[k0n + 7];  Q3 = xs[k0n + 8];
                    R0 = xs[k0n + 9];  R1 = xs[k0n + 10]; R2 = xs[k0n + 11]; R3 = xs[k0n + 12];
                }
                { const int pe = km < TVW - 1 ? km : TVW - 1;
                  if (!hi) for (int p = k0 + l32; p <= pe; p += 32) x[p] = wv; }
                if (k0n >= TVW) goto done;
                // lo: u'=lam, v'=nv ; hi: U'=(-nv-lam)-V_old, V'=V_old
                tt = nv - lam;
                u = hi ? (tt - v) : lam;
                v = hi ? v : nv;
                k0 = k0n; km = k0n;
                goto seg_start;
            } else if ((unsigned)(bb >> 32)) { // flush [k0..kp] at vmax; keep vmin/km
                const int k0n = kp + 1;
                wv = -v;                     // hi lanes hold -vmax natively
                if (k0n < TVW) {
                    nv = xs[k0n];
                    P0 = xs[k0n + 1];  P1 = xs[k0n + 2];  P2 = xs[k0n + 3];  P3 = xs[k0n + 4];
                    Q0 = xs[k0n + 5];  Q1 = xs[k0n + 6];  Q2 = xs[k0n + 7];  Q3 = xs[k0n + 8];
                    R0 = xs[k0n + 9];  R1 = xs[k0n + 10]; R2 = xs[k0n + 11]; R3 = xs[k0n + 12];
                }
                { const int pe = kp < TVW - 1 ? kp : TVW - 1;
                  if (hi) for (int p = k0 + l32; p <= pe; p += 32) x[p] = wv; }
                if (k0n >= TVW) goto done;
                // lo: u'=(nv-lam)-vmin, v'=vmin ; hi: U'=lam, V'=-nv
                tt = nv - lam;
                u = hi ? lam : (tt - v);
                v = hi ? nv : v;
                k0 = k0n; kp = k0n;
                goto seg_start;
            } else {                         // terminate: flush tail at mean value
                const float vt = fmaf(u, __builtin_amdgcn_rcpf((float)(trips + 1)), v);
                if (!hi) for (int p = k0 + l32; p < TVW; p += 32) x[p] = vt;
                goto done;
            }
        }

midjump: // jump while absorbing; jb lo bits = negative (priority), hi = positive
        {
            negj = (unsigned)jb != 0;
            const int fe = negj ? km : kp;   // flush end (scalar); fe <= W-2 here
            const int k0n = fe + 1;
            wv = hi ? -v : v;                // value this half would write (pre-restart)
            nv = xs[k0n];                    // refill issued before the stores
            P0 = xs[k0n + 1];  P1 = xs[k0n + 2];  P2 = xs[k0n + 3];  P3 = xs[k0n + 4];
            Q0 = xs[k0n + 5];  Q1 = xs[k0n + 6];  Q2 = xs[k0n + 7];  Q3 = xs[k0n + 8];
            R0 = xs[k0n + 9];  R1 = xs[k0n + 10]; R2 = xs[k0n + 11]; R3 = xs[k0n + 12];
            // neg jump -> lo half writes vmin; pos jump -> hi half writes vmax
            if (negj != hi) {
                for (int p = k0 + l32; p <= fe; p += 32) x[p] = wv;
            }
            k0 = k0n; km = k0n; kp = k0n;
            v = nv - (negj ? cneg : cpos);   // lo/hi restart values (v8 algebra)
            u = lam;
            goto seg_start;
        }
#undef TVPHASE
#undef TVSTEP
done:   ;
        // ---- per-wave coalesced float4 writeback LDS -> out ----
        {
            const float4* b4 = (const float4*)(buf + wave * TVW);
            float4* d4 = (float4*)(out + (size_t)row * TVW);
            #pragma unroll
            for (int i = 0; i < TVW / 4; i += 64)
                d4[i + lane] = b4[i + lane];
        }
    }
}

extern "C" void kernel_launch(void* const* d_in, const int* in_sizes, int n_in,
                              void* d_out, int out_size, void* d_ws, size_t ws_size,
                              hipStream_t stream) {
    const float* y    = (const float*)d_in[0];
    const float* lmbd = (const float*)d_in[1];
    float* out = (float*)d_out;

    const int total_rows = in_sizes[0] / TVW;              // 6144
    const int grid = (total_rows + WPB - 1) / WPB;         // 3072 blocks
    tv1d_condat_wave_kernel<<<grid, BLOCK, 0, stream>>>(y, lmbd, out, total_rows);
}